// Round 9
// baseline (379.086 us; speedup 1.0000x reference)
//
#include <hip/hip_runtime.h>
#include <hip/hip_bf16.h>

#define BB 2048
#define NN 256
#define EE 32
#define HH 64

typedef __attribute__((ext_vector_type(8))) short s16x8;   // 8 bf16 = MFMA A/B frag
typedef __attribute__((ext_vector_type(4))) short s16x4;
typedef __attribute__((ext_vector_type(4))) float f32x4;   // MFMA C/D frag

__device__ __forceinline__ unsigned short f32_to_bf16_rne(float f) {
    unsigned int u = __float_as_uint(f);
    unsigned int r = u + 0x7FFFu + ((u >> 16) & 1u);
    return (unsigned short)(r >> 16);
}
__device__ __forceinline__ float bf16_to_f32(unsigned short h) {
    return __uint_as_float(((unsigned int)h) << 16);
}

// ---------------------------------------------------------------------------
// Split x into hi/lo bf16 (once; L2-resident afterwards). [validated r8]
// ---------------------------------------------------------------------------
__global__ void prep_x(const float* __restrict__ x,
                       unsigned short* __restrict__ xh,
                       unsigned short* __restrict__ xl) {
    const int i4 = (blockIdx.x * 256 + threadIdx.x) * 4;
    const f32x4 v = *(const f32x4*)(x + i4);
    s16x4 hv, lv;
    #pragma unroll
    for (int q = 0; q < 4; ++q) {
        const unsigned short hb = f32_to_bf16_rne(v[q]);
        hv[q] = (short)hb;
        lv[q] = (short)f32_to_bf16_rne(v[q] - bf16_to_f32(hb));
    }
    *(s16x4*)(xh + i4) = hv;
    *(s16x4*)(xl + i4) = lv;
}

// ---------------------------------------------------------------------------
// Parallel c precompute. [validated r8]
// ---------------------------------------------------------------------------
__global__ __launch_bounds__(256) void precompute_c(
    const float* __restrict__ A, const float* __restrict__ emb,
    const float* __restrict__ W1, const float* __restrict__ b1,
    float* __restrict__ c) {
    const int i = blockIdx.x;
    const int t = threadIdx.x;
    __shared__ float aS[NN];
    __shared__ float red[256];
    __shared__ float peS[EE];

    const float a_t = A[t * NN + i];
    aS[t] = a_t;
    red[t] = a_t;
    __syncthreads();
    #pragma unroll
    for (int s = 128; s > 0; s >>= 1) {
        if (t < s) red[t] += red[t + s];
        __syncthreads();
    }
    const float inv = 1.f / (red[0] + 1e-8f);

    const int e = t & 31, jg = t >> 5;
    float part = 0.f;
    #pragma unroll 8
    for (int r = 0; r < 32; ++r) {
        const int j = jg * 32 + r;
        part = fmaf(aS[j], emb[j * EE + e], part);
    }
    __syncthreads();
    red[t] = part;
    __syncthreads();
    if (t < 32) {
        float pe = 0.f;
        #pragma unroll
        for (int g = 0; g < 8; ++g) pe += red[g * 32 + t];
        peS[t] = pe * inv;
    }
    __syncthreads();

    if (t < HH) {
        float ch = b1[t];
        const float* embi = emb + i * EE;
        #pragma unroll 8
        for (int e2 = 0; e2 < EE; ++e2) {
            ch = fmaf(embi[e2], W1[(NN      + e2) * HH + t], ch);
            ch = fmaf(peS[e2],  W1[(NN + EE + e2) * HH + t], ch);
        }
        c[i * HH + t] = ch;
    }
}

// ---------------------------------------------------------------------------
// Fused main, TWO-PASS over h (r9 change): per pass fold 2 n-tiles of
// W1s = diag(A[:,i])*W1 (Bh+Bl = 32 KB), full kb MFMA loop into acc[4][2],
// transpose 32-col h1 chunk through 32 KB overlay -> acc1 chunk.
// LDS 66.5 -> 33 KB => 4 blocks/CU (was 2): occupancy fix for the 52% stall.
// Fragment layouts / swizzle / 3-term split / epilogue: validated r7/r8.
// ---------------------------------------------------------------------------
__global__ __launch_bounds__(256, 4) void fused_main(
    const unsigned short* __restrict__ xh, const unsigned short* __restrict__ xl,
    const float* __restrict__ A, const float* __restrict__ W1,
    const float* __restrict__ c,
    const float* __restrict__ g1, const float* __restrict__ bt1,
    const float* __restrict__ W2, const float* __restrict__ b2,
    const float* __restrict__ g2, const float* __restrict__ bt2,
    const float* __restrict__ W3, const float* __restrict__ b3,
    float* __restrict__ out) {

    __shared__ float smem[8192];       // 32 KB: {Bh 16K | Bl 16K} / overlay tr
    __shared__ float aS[NN];           // 1 KB: A[:,i]
    unsigned short* Bh = (unsigned short*)smem;          // 16 frags * 512
    unsigned short* Bl = Bh + 16 * 512;
    float* tr = smem;                                    // [256][32] swizzled

    const int t  = threadIdx.x;
    const int i  = blockIdx.x & 255;          // consecutive blocks share x rows
    const int b0 = (blockIdx.x >> 8) * 256;

    const int l  = t & 63;
    const int wv = t >> 6;
    const int lg = l >> 4;
    const int lm = l & 15;

    aS[t] = A[t * NN + i];
    __syncthreads();

    float acc1[HH];

    #pragma unroll
    for (int p = 0; p < 2; ++p) {
        // ---- fold pass-p half of W1s into frag-linear split-bf16 LDS ----
        // frag f = kb*2 + ntl (16 frags); thread covers lane l of 4 frags.
        #pragma unroll
        for (int fr = 0; fr < 4; ++fr) {
            const int f   = wv * 4 + fr;
            const int kb  = f >> 1, ntl = f & 1;
            const int h   = p * 32 + ntl * 16 + lm;
            const int jb  = kb * 32 + lg * 8;
            s16x8 hv, lv;
            #pragma unroll
            for (int w = 0; w < 8; ++w) {
                const int j = jb + w;
                const float pw = aS[j] * W1[j * HH + h];
                const unsigned short hb = f32_to_bf16_rne(pw);
                hv[w] = (short)hb;
                lv[w] = (short)f32_to_bf16_rne(pw - bf16_to_f32(hb));
            }
            *(s16x8*)(Bh + f * 512 + l * 8) = hv;
            *(s16x8*)(Bl + f * 512 + l * 8) = lv;
        }
        __syncthreads();

        // ---- MFMA loop: acc[rt][ntl] over 8 kb ----
        f32x4 acc[4][2];
        #pragma unroll
        for (int rt = 0; rt < 4; ++rt)
            #pragma unroll
            for (int n = 0; n < 2; ++n) {
                acc[rt][n][0] = 0.f; acc[rt][n][1] = 0.f;
                acc[rt][n][2] = 0.f; acc[rt][n][3] = 0.f;
            }

        const int rowbase = b0 + wv * 64;
        for (int kb = 0; kb < 8; ++kb) {
            s16x8 bh[2], bl[2];
            #pragma unroll
            for (int n = 0; n < 2; ++n) {
                const int sbase = ((kb * 2 + n) * 64 + l) * 8;
                bh[n] = *(const s16x8*)(Bh + sbase);
                bl[n] = *(const s16x8*)(Bl + sbase);
            }
            const int koff = kb * 32 + lg * 8;
            #pragma unroll
            for (int rt = 0; rt < 4; ++rt) {
                const int row = rowbase + rt * 16 + lm;
                const s16x8 ah = *(const s16x8*)(xh + row * NN + koff);
                const s16x8 al = *(const s16x8*)(xl + row * NN + koff);
                #pragma unroll
                for (int n = 0; n < 2; ++n) {
                    acc[rt][n] = __builtin_amdgcn_mfma_f32_16x16x32_bf16(ah, bh[n], acc[rt][n], 0, 0, 0);
                    acc[rt][n] = __builtin_amdgcn_mfma_f32_16x16x32_bf16(ah, bl[n], acc[rt][n], 0, 0, 0);
                    acc[rt][n] = __builtin_amdgcn_mfma_f32_16x16x32_bf16(al, bh[n], acc[rt][n], 0, 0, 0);
                }
            }
        }
        __syncthreads();   // B reads done; safe to overlay tr

        // ---- C-frags -> swizzled 32-col tr chunk ----
        #pragma unroll
        for (int rt = 0; rt < 4; ++rt) {
            #pragma unroll
            for (int n = 0; n < 2; ++n) {
                #pragma unroll
                for (int rr = 0; rr < 4; ++rr) {
                    const int wr  = wv * 64 + rt * 16 + lg * 4 + rr;
                    const int col = n * 16 + lm;                 // 0..31
                    const int q   = col >> 2;                    // 0..7
                    tr[wr * 32 + (((q ^ (wr & 7)) << 2) | (col & 3))] = acc[rt][n][rr];
                }
            }
        }
        __syncthreads();

        // ---- read back row t's 32-col chunk ----
        #pragma unroll
        for (int g = 0; g < 8; ++g) {
            const f32x4 v = *(const f32x4*)&tr[t * 32 + ((g ^ (t & 7)) << 2)];
            acc1[p*32 + 4*g + 0] = v[0]; acc1[p*32 + 4*g + 1] = v[1];
            acc1[p*32 + 4*g + 2] = v[2]; acc1[p*32 + 4*g + 3] = v[3];
        }
        __syncthreads();   // protect tr before next pass's fold overwrites
    }

    // ---- validated epilogue (thread t owns b-row b0+t, node i) ----
    {
        const float* crow = c + i * HH;
        #pragma unroll
        for (int h = 0; h < HH; ++h) acc1[h] += crow[h];
    }

    // LayerNorm 1 + leaky relu
    {
        float m0 = 0.f, m1 = 0.f, m2 = 0.f, m3 = 0.f;
        #pragma unroll
        for (int h = 0; h < HH; h += 4) { m0 += acc1[h]; m1 += acc1[h+1]; m2 += acc1[h+2]; m3 += acc1[h+3]; }
        const float m = (m0 + m1 + m2 + m3) * (1.f / HH);
        float v0 = 0.f, v1 = 0.f, v2 = 0.f, v3 = 0.f;
        #pragma unroll
        for (int h = 0; h < HH; h += 4) {
            float d0 = acc1[h] - m, d1 = acc1[h+1] - m, d2 = acc1[h+2] - m, d3 = acc1[h+3] - m;
            v0 = fmaf(d0, d0, v0); v1 = fmaf(d1, d1, v1); v2 = fmaf(d2, d2, v2); v3 = fmaf(d3, d3, v3);
        }
        const float var = (v0 + v1 + v2 + v3) * (1.f / HH);
        const float inv = rsqrtf(var + 1e-5f);
        #pragma unroll
        for (int h = 0; h < HH; ++h) {
            float u = (acc1[h] - m) * inv * g1[h] + bt1[h];
            acc1[h] = (u >= 0.f) ? u : 0.2f * u;
        }
    }

    // Layer 2 (fully unrolled)
    float acc2[HH];
    #pragma unroll
    for (int ho = 0; ho < HH; ++ho) acc2[ho] = b2[ho];
    #pragma unroll
    for (int h = 0; h < HH; ++h) {
        const float v = acc1[h];
        const float* w = W2 + h * HH;
        #pragma unroll
        for (int ho = 0; ho < HH; ++ho) acc2[ho] = fmaf(v, w[ho], acc2[ho]);
    }

    // LayerNorm 2 + leaky
    {
        float m0 = 0.f, m1 = 0.f, m2 = 0.f, m3 = 0.f;
        #pragma unroll
        for (int h = 0; h < HH; h += 4) { m0 += acc2[h]; m1 += acc2[h+1]; m2 += acc2[h+2]; m3 += acc2[h+3]; }
        const float m = (m0 + m1 + m2 + m3) * (1.f / HH);
        float v0 = 0.f, v1 = 0.f, v2 = 0.f, v3 = 0.f;
        #pragma unroll
        for (int h = 0; h < HH; h += 4) {
            float d0 = acc2[h] - m, d1 = acc2[h+1] - m, d2 = acc2[h+2] - m, d3 = acc2[h+3] - m;
            v0 = fmaf(d0, d0, v0); v1 = fmaf(d1, d1, v1); v2 = fmaf(d2, d2, v2); v3 = fmaf(d3, d3, v3);
        }
        const float var = (v0 + v1 + v2 + v3) * (1.f / HH);
        const float inv = rsqrtf(var + 1e-5f);
        #pragma unroll
        for (int h = 0; h < HH; ++h) {
            float u = (acc2[h] - m) * inv * g2[h] + bt2[h];
            acc2[h] = (u >= 0.f) ? u : 0.2f * u;
        }
    }

    // Layer 3
    float o0 = b3[0], o1 = b3[1];
    #pragma unroll
    for (int h = 0; h < HH; ++h) {
        o0 = fmaf(acc2[h], W3[h * 2 + 0], o0);
        o1 = fmaf(acc2[h], W3[h * 2 + 1], o1);
    }

    const int row = (b0 + t) * NN + i;
    out[row] = o0;
    out[BB * NN + row] = o1;
}

extern "C" void kernel_launch(void* const* d_in, const int* in_sizes, int n_in,
                              void* d_out, int out_size, void* d_ws, size_t ws_size,
                              hipStream_t stream) {
    const float* x   = (const float*)d_in[0];
    const float* A   = (const float*)d_in[1];
    const float* emb = (const float*)d_in[2];
    const float* W1  = (const float*)d_in[3];
    const float* b1  = (const float*)d_in[4];
    const float* g1  = (const float*)d_in[5];
    const float* bt1 = (const float*)d_in[6];
    const float* W2  = (const float*)d_in[7];
    const float* b2  = (const float*)d_in[8];
    const float* g2  = (const float*)d_in[9];
    const float* bt2 = (const float*)d_in[10];
    const float* W3  = (const float*)d_in[11];
    const float* b3  = (const float*)d_in[12];
    float* out = (float*)d_out;

    // ws carve: c (64 KB) | xh (1 MB) | xl (1 MB)
    float* c = (float*)d_ws;
    unsigned short* xhp = (unsigned short*)(c + NN * HH);
    unsigned short* xlp = xhp + BB * NN;

    prep_x<<<(BB * NN) / 1024, 256, 0, stream>>>(x, xhp, xlp);
    precompute_c<<<NN, 256, 0, stream>>>(A, emb, W1, b1, c);
    fused_main<<<NN * (BB / 256), 256, 0, stream>>>(
        xhp, xlp, A, W1, c, g1, bt1, W2, b2, g2, bt2, W3, b3, out);
}

// Round 10
// 295.628 us; speedup vs baseline: 1.2823x; 1.2823x over previous
//
#include <hip/hip_runtime.h>
#include <hip/hip_bf16.h>

#define BB 2048
#define NN 256
#define EE 32
#define HH 64

typedef __attribute__((ext_vector_type(8))) short s16x8;   // 8 bf16 = MFMA A/B frag
typedef __attribute__((ext_vector_type(4))) short s16x4;
typedef __attribute__((ext_vector_type(4))) float f32x4;   // MFMA C/D frag

__device__ __forceinline__ unsigned short f32_to_bf16_rne(float f) {
    unsigned int u = __float_as_uint(f);
    unsigned int r = u + 0x7FFFu + ((u >> 16) & 1u);
    return (unsigned short)(r >> 16);
}
__device__ __forceinline__ float bf16_to_f32(unsigned short h) {
    return __uint_as_float(((unsigned int)h) << 16);
}

// ---------------------------------------------------------------------------
// Split x into hi/lo bf16 (once; L2-resident afterwards). [validated r8]
// ---------------------------------------------------------------------------
__global__ void prep_x(const float* __restrict__ x,
                       unsigned short* __restrict__ xh,
                       unsigned short* __restrict__ xl) {
    const int i4 = (blockIdx.x * 256 + threadIdx.x) * 4;
    const f32x4 v = *(const f32x4*)(x + i4);
    s16x4 hv, lv;
    #pragma unroll
    for (int q = 0; q < 4; ++q) {
        const unsigned short hb = f32_to_bf16_rne(v[q]);
        hv[q] = (short)hb;
        lv[q] = (short)f32_to_bf16_rne(v[q] - bf16_to_f32(hb));
    }
    *(s16x4*)(xh + i4) = hv;
    *(s16x4*)(xl + i4) = lv;
}

// ---------------------------------------------------------------------------
// Parallel c precompute. [validated r8]
// ---------------------------------------------------------------------------
__global__ __launch_bounds__(256) void precompute_c(
    const float* __restrict__ A, const float* __restrict__ emb,
    const float* __restrict__ W1, const float* __restrict__ b1,
    float* __restrict__ c) {
    const int i = blockIdx.x;
    const int t = threadIdx.x;
    __shared__ float aS[NN];
    __shared__ float red[256];
    __shared__ float peS[EE];

    const float a_t = A[t * NN + i];
    aS[t] = a_t;
    red[t] = a_t;
    __syncthreads();
    #pragma unroll
    for (int s = 128; s > 0; s >>= 1) {
        if (t < s) red[t] += red[t + s];
        __syncthreads();
    }
    const float inv = 1.f / (red[0] + 1e-8f);

    const int e = t & 31, jg = t >> 5;
    float part = 0.f;
    #pragma unroll 8
    for (int r = 0; r < 32; ++r) {
        const int j = jg * 32 + r;
        part = fmaf(aS[j], emb[j * EE + e], part);
    }
    __syncthreads();
    red[t] = part;
    __syncthreads();
    if (t < 32) {
        float pe = 0.f;
        #pragma unroll
        for (int g = 0; g < 8; ++g) pe += red[g * 32 + t];
        peS[t] = pe * inv;
    }
    __syncthreads();

    if (t < HH) {
        float ch = b1[t];
        const float* embi = emb + i * EE;
        #pragma unroll 8
        for (int e2 = 0; e2 < EE; ++e2) {
            ch = fmaf(embi[e2], W1[(NN      + e2) * HH + t], ch);
            ch = fmaf(peS[e2],  W1[(NN + EE + e2) * HH + t], ch);
        }
        c[i * HH + t] = ch;
    }
}

// ---------------------------------------------------------------------------
// Fused main, two-pass over h (33 KB LDS -> 4 blocks/CU, validated r9) with
// __launch_bounds__(256,2) (r10 fix): r9's (256,4) made the allocator clamp
// VGPR to 64 -> acc1/acc2 spilled (519 MB scratch writebacks, 317us). (256,2)
// caps at 256; this epilogue measured 116 VGPR under it in r8 -> <=128 tier
// -> HW still reaches 4 waves/SIMD; allocator minimum no longer forces spill.
// Fragment layouts / swizzle / 3-term split / epilogue: validated r7/r8.
// ---------------------------------------------------------------------------
__global__ __launch_bounds__(256, 2) void fused_main(
    const unsigned short* __restrict__ xh, const unsigned short* __restrict__ xl,
    const float* __restrict__ A, const float* __restrict__ W1,
    const float* __restrict__ c,
    const float* __restrict__ g1, const float* __restrict__ bt1,
    const float* __restrict__ W2, const float* __restrict__ b2,
    const float* __restrict__ g2, const float* __restrict__ bt2,
    const float* __restrict__ W3, const float* __restrict__ b3,
    float* __restrict__ out) {

    __shared__ float smem[8192];       // 32 KB: {Bh 16K | Bl 16K} / overlay tr
    __shared__ float aS[NN];           // 1 KB: A[:,i]
    unsigned short* Bh = (unsigned short*)smem;          // 16 frags * 512
    unsigned short* Bl = Bh + 16 * 512;
    float* tr = smem;                                    // [256][32] swizzled

    const int t  = threadIdx.x;
    const int i  = blockIdx.x & 255;          // consecutive blocks share x rows
    const int b0 = (blockIdx.x >> 8) * 256;

    const int l  = t & 63;
    const int wv = t >> 6;
    const int lg = l >> 4;
    const int lm = l & 15;

    aS[t] = A[t * NN + i];
    __syncthreads();

    float acc1[HH];

    #pragma unroll
    for (int p = 0; p < 2; ++p) {
        // ---- fold pass-p half of W1s into frag-linear split-bf16 LDS ----
        #pragma unroll
        for (int fr = 0; fr < 4; ++fr) {
            const int f   = wv * 4 + fr;
            const int kb  = f >> 1, ntl = f & 1;
            const int h   = p * 32 + ntl * 16 + lm;
            const int jb  = kb * 32 + lg * 8;
            s16x8 hv, lv;
            #pragma unroll
            for (int w = 0; w < 8; ++w) {
                const int j = jb + w;
                const float pw = aS[j] * W1[j * HH + h];
                const unsigned short hb = f32_to_bf16_rne(pw);
                hv[w] = (short)hb;
                lv[w] = (short)f32_to_bf16_rne(pw - bf16_to_f32(hb));
            }
            *(s16x8*)(Bh + f * 512 + l * 8) = hv;
            *(s16x8*)(Bl + f * 512 + l * 8) = lv;
        }
        __syncthreads();

        // ---- MFMA loop: acc[rt][ntl] over 8 kb ----
        f32x4 acc[4][2];
        #pragma unroll
        for (int rt = 0; rt < 4; ++rt)
            #pragma unroll
            for (int n = 0; n < 2; ++n) {
                acc[rt][n][0] = 0.f; acc[rt][n][1] = 0.f;
                acc[rt][n][2] = 0.f; acc[rt][n][3] = 0.f;
            }

        const int rowbase = b0 + wv * 64;
        for (int kb = 0; kb < 8; ++kb) {
            s16x8 bh[2], bl[2];
            #pragma unroll
            for (int n = 0; n < 2; ++n) {
                const int sbase = ((kb * 2 + n) * 64 + l) * 8;
                bh[n] = *(const s16x8*)(Bh + sbase);
                bl[n] = *(const s16x8*)(Bl + sbase);
            }
            const int koff = kb * 32 + lg * 8;
            #pragma unroll
            for (int rt = 0; rt < 4; ++rt) {
                const int row = rowbase + rt * 16 + lm;
                const s16x8 ah = *(const s16x8*)(xh + row * NN + koff);
                const s16x8 al = *(const s16x8*)(xl + row * NN + koff);
                #pragma unroll
                for (int n = 0; n < 2; ++n) {
                    acc[rt][n] = __builtin_amdgcn_mfma_f32_16x16x32_bf16(ah, bh[n], acc[rt][n], 0, 0, 0);
                    acc[rt][n] = __builtin_amdgcn_mfma_f32_16x16x32_bf16(ah, bl[n], acc[rt][n], 0, 0, 0);
                    acc[rt][n] = __builtin_amdgcn_mfma_f32_16x16x32_bf16(al, bh[n], acc[rt][n], 0, 0, 0);
                }
            }
        }
        __syncthreads();   // B reads done; safe to overlay tr

        // ---- C-frags -> swizzled 32-col tr chunk ----
        #pragma unroll
        for (int rt = 0; rt < 4; ++rt) {
            #pragma unroll
            for (int n = 0; n < 2; ++n) {
                #pragma unroll
                for (int rr = 0; rr < 4; ++rr) {
                    const int wr  = wv * 64 + rt * 16 + lg * 4 + rr;
                    const int col = n * 16 + lm;                 // 0..31
                    const int q   = col >> 2;                    // 0..7
                    tr[wr * 32 + (((q ^ (wr & 7)) << 2) | (col & 3))] = acc[rt][n][rr];
                }
            }
        }
        __syncthreads();

        // ---- read back row t's 32-col chunk ----
        #pragma unroll
        for (int g = 0; g < 8; ++g) {
            const f32x4 v = *(const f32x4*)&tr[t * 32 + ((g ^ (t & 7)) << 2)];
            acc1[p*32 + 4*g + 0] = v[0]; acc1[p*32 + 4*g + 1] = v[1];
            acc1[p*32 + 4*g + 2] = v[2]; acc1[p*32 + 4*g + 3] = v[3];
        }
        __syncthreads();   // protect tr before next pass's fold overwrites
    }

    // ---- validated epilogue (thread t owns b-row b0+t, node i) ----
    {
        const float* crow = c + i * HH;
        #pragma unroll
        for (int h = 0; h < HH; ++h) acc1[h] += crow[h];
    }

    // LayerNorm 1 + leaky relu
    {
        float m0 = 0.f, m1 = 0.f, m2 = 0.f, m3 = 0.f;
        #pragma unroll
        for (int h = 0; h < HH; h += 4) { m0 += acc1[h]; m1 += acc1[h+1]; m2 += acc1[h+2]; m3 += acc1[h+3]; }
        const float m = (m0 + m1 + m2 + m3) * (1.f / HH);
        float v0 = 0.f, v1 = 0.f, v2 = 0.f, v3 = 0.f;
        #pragma unroll
        for (int h = 0; h < HH; h += 4) {
            float d0 = acc1[h] - m, d1 = acc1[h+1] - m, d2 = acc1[h+2] - m, d3 = acc1[h+3] - m;
            v0 = fmaf(d0, d0, v0); v1 = fmaf(d1, d1, v1); v2 = fmaf(d2, d2, v2); v3 = fmaf(d3, d3, v3);
        }
        const float var = (v0 + v1 + v2 + v3) * (1.f / HH);
        const float inv = rsqrtf(var + 1e-5f);
        #pragma unroll
        for (int h = 0; h < HH; ++h) {
            float u = (acc1[h] - m) * inv * g1[h] + bt1[h];
            acc1[h] = (u >= 0.f) ? u : 0.2f * u;
        }
    }

    // Layer 2 (fully unrolled)
    float acc2[HH];
    #pragma unroll
    for (int ho = 0; ho < HH; ++ho) acc2[ho] = b2[ho];
    #pragma unroll
    for (int h = 0; h < HH; ++h) {
        const float v = acc1[h];
        const float* w = W2 + h * HH;
        #pragma unroll
        for (int ho = 0; ho < HH; ++ho) acc2[ho] = fmaf(v, w[ho], acc2[ho]);
    }

    // LayerNorm 2 + leaky
    {
        float m0 = 0.f, m1 = 0.f, m2 = 0.f, m3 = 0.f;
        #pragma unroll
        for (int h = 0; h < HH; h += 4) { m0 += acc2[h]; m1 += acc2[h+1]; m2 += acc2[h+2]; m3 += acc2[h+3]; }
        const float m = (m0 + m1 + m2 + m3) * (1.f / HH);
        float v0 = 0.f, v1 = 0.f, v2 = 0.f, v3 = 0.f;
        #pragma unroll
        for (int h = 0; h < HH; h += 4) {
            float d0 = acc2[h] - m, d1 = acc2[h+1] - m, d2 = acc2[h+2] - m, d3 = acc2[h+3] - m;
            v0 = fmaf(d0, d0, v0); v1 = fmaf(d1, d1, v1); v2 = fmaf(d2, d2, v2); v3 = fmaf(d3, d3, v3);
        }
        const float var = (v0 + v1 + v2 + v3) * (1.f / HH);
        const float inv = rsqrtf(var + 1e-5f);
        #pragma unroll
        for (int h = 0; h < HH; ++h) {
            float u = (acc2[h] - m) * inv * g2[h] + bt2[h];
            acc2[h] = (u >= 0.f) ? u : 0.2f * u;
        }
    }

    // Layer 3
    float o0 = b3[0], o1 = b3[1];
    #pragma unroll
    for (int h = 0; h < HH; ++h) {
        o0 = fmaf(acc2[h], W3[h * 2 + 0], o0);
        o1 = fmaf(acc2[h], W3[h * 2 + 1], o1);
    }

    const int row = (b0 + t) * NN + i;
    out[row] = o0;
    out[BB * NN + row] = o1;
}

extern "C" void kernel_launch(void* const* d_in, const int* in_sizes, int n_in,
                              void* d_out, int out_size, void* d_ws, size_t ws_size,
                              hipStream_t stream) {
    const float* x   = (const float*)d_in[0];
    const float* A   = (const float*)d_in[1];
    const float* emb = (const float*)d_in[2];
    const float* W1  = (const float*)d_in[3];
    const float* b1  = (const float*)d_in[4];
    const float* g1  = (const float*)d_in[5];
    const float* bt1 = (const float*)d_in[6];
    const float* W2  = (const float*)d_in[7];
    const float* b2  = (const float*)d_in[8];
    const float* g2  = (const float*)d_in[9];
    const float* bt2 = (const float*)d_in[10];
    const float* W3  = (const float*)d_in[11];
    const float* b3  = (const float*)d_in[12];
    float* out = (float*)d_out;

    // ws carve: c (64 KB) | xh (1 MB) | xl (1 MB)
    float* c = (float*)d_ws;
    unsigned short* xhp = (unsigned short*)(c + NN * HH);
    unsigned short* xlp = xhp + BB * NN;

    prep_x<<<(BB * NN) / 1024, 256, 0, stream>>>(x, xhp, xlp);
    precompute_c<<<NN, 256, 0, stream>>>(A, emb, W1, b1, c);
    fused_main<<<NN * (BB / 256), 256, 0, stream>>>(
        xhp, xlp, A, W1, c, g1, bt1, W2, b2, g2, bt2, W3, b3, out);
}

// Round 12
// 196.825 us; speedup vs baseline: 1.9260x; 1.5020x over previous
//
#include <hip/hip_runtime.h>
#include <hip/hip_bf16.h>

#define BB 2048
#define NN 256
#define EE 32
#define HH 64

typedef __attribute__((ext_vector_type(8))) short s16x8;   // 8 bf16 = MFMA A/B frag
typedef __attribute__((ext_vector_type(4))) short s16x4;
typedef __attribute__((ext_vector_type(4))) float f32x4;   // MFMA C/D frag

__device__ __forceinline__ unsigned short f32_to_bf16_rne(float f) {
    unsigned int u = __float_as_uint(f);
    unsigned int r = u + 0x7FFFu + ((u >> 16) & 1u);
    return (unsigned short)(r >> 16);
}
__device__ __forceinline__ float bf16_to_f32(unsigned short h) {
    return __uint_as_float(((unsigned int)h) << 16);
}

// ---------------------------------------------------------------------------
// Split x into hi/lo bf16 (once; L2-resident afterwards). [validated r8]
// ---------------------------------------------------------------------------
__global__ void prep_x(const float* __restrict__ x,
                       unsigned short* __restrict__ xh,
                       unsigned short* __restrict__ xl) {
    const int i4 = (blockIdx.x * 256 + threadIdx.x) * 4;
    const f32x4 v = *(const f32x4*)(x + i4);
    s16x4 hv, lv;
    #pragma unroll
    for (int q = 0; q < 4; ++q) {
        const unsigned short hb = f32_to_bf16_rne(v[q]);
        hv[q] = (short)hb;
        lv[q] = (short)f32_to_bf16_rne(v[q] - bf16_to_f32(hb));
    }
    *(s16x4*)(xh + i4) = hv;
    *(s16x4*)(xl + i4) = lv;
}

// ---------------------------------------------------------------------------
// Split W2^T into hi/lo bf16: w2t[n][k] = split(W2[k][n]).  (r11 new; same
// pattern as r7's validated prep_w1t.)  16 blocks x 256 thr, 1 elem each.
// ---------------------------------------------------------------------------
__global__ void prep_w2t(const float* __restrict__ W2,
                         unsigned short* __restrict__ w2h,
                         unsigned short* __restrict__ w2l) {
    const int idx = blockIdx.x * 256 + threadIdx.x;   // 0..4095
    const int n = idx >> 6, k = idx & 63;
    const float w = W2[k * HH + n];
    const unsigned short hb = f32_to_bf16_rne(w);
    w2h[n * HH + k] = hb;
    w2l[n * HH + k] = f32_to_bf16_rne(w - bf16_to_f32(hb));
}

// ---------------------------------------------------------------------------
// Parallel c precompute. [validated r8]
// ---------------------------------------------------------------------------
__global__ __launch_bounds__(256) void precompute_c(
    const float* __restrict__ A, const float* __restrict__ emb,
    const float* __restrict__ W1, const float* __restrict__ b1,
    float* __restrict__ c) {
    const int i = blockIdx.x;
    const int t = threadIdx.x;
    __shared__ float aS[NN];
    __shared__ float red[256];
    __shared__ float peS[EE];

    const float a_t = A[t * NN + i];
    aS[t] = a_t;
    red[t] = a_t;
    __syncthreads();
    #pragma unroll
    for (int s = 128; s > 0; s >>= 1) {
        if (t < s) red[t] += red[t + s];
        __syncthreads();
    }
    const float inv = 1.f / (red[0] + 1e-8f);

    const int e = t & 31, jg = t >> 5;
    float part = 0.f;
    #pragma unroll 8
    for (int r = 0; r < 32; ++r) {
        const int j = jg * 32 + r;
        part = fmaf(aS[j], emb[j * EE + e], part);
    }
    __syncthreads();
    red[t] = part;
    __syncthreads();
    if (t < 32) {
        float pe = 0.f;
        #pragma unroll
        for (int g = 0; g < 8; ++g) pe += red[g * 32 + t];
        peS[t] = pe * inv;
    }
    __syncthreads();

    if (t < HH) {
        float ch = b1[t];
        const float* embi = emb + i * EE;
        #pragma unroll 8
        for (int e2 = 0; e2 < EE; ++e2) {
            ch = fmaf(embi[e2], W1[(NN      + e2) * HH + t], ch);
            ch = fmaf(peS[e2],  W1[(NN + EE + e2) * HH + t], ch);
        }
        c[i * HH + t] = ch;
    }
}

// ---------------------------------------------------------------------------
// Fused main (r11): r8 one-pass structure (best known, 174us) + layer-2 on
// MFMA. r10 lesson: register file (VGPR+AGPR, not the reported VGPR_Count)
// caps residency at 2 blocks/CU; two-pass LDS shrink bought nothing. So keep
// 64KB LDS and instead remove the biggest busy item: layer-2's 4096 serial
// fmac/thread (~27us busy) -> 96 MFMA/wave via LDS A-frag scatter + global
// split-W2t B-frags. 3-term hi/lo split as validated (absmax unchanged).
// Sequence (one 64KB union, 9 barriers):
//   fold B1 -> MFMA1 -> tr1 -> rows -> LN1 -> scatter A2 -> MFMA2 -> tr2
//   -> rows -> LN2 -> W3 -> store.
// ---------------------------------------------------------------------------
__global__ __launch_bounds__(256, 2) void fused_main(
    const unsigned short* __restrict__ xh, const unsigned short* __restrict__ xl,
    const float* __restrict__ A, const float* __restrict__ W1,
    const float* __restrict__ c,
    const unsigned short* __restrict__ w2h, const unsigned short* __restrict__ w2l,
    const float* __restrict__ g1, const float* __restrict__ bt1,
    const float* __restrict__ b2,
    const float* __restrict__ g2, const float* __restrict__ bt2,
    const float* __restrict__ W3, const float* __restrict__ b3,
    float* __restrict__ out) {

    __shared__ float smem[16384];      // 64 KB union: B1 / tr / A2
    __shared__ float aS[NN];           // A[:,i]
    unsigned short* Bh = (unsigned short*)smem;   // 32 frags * 512 shorts
    unsigned short* Bl = Bh + 32 * 512;
    float* tr = smem;                             // [256][64] swizzled
    unsigned short* Ah = (unsigned short*)smem;   // layer-2 A frags
    unsigned short* Al = Ah + 32 * 512;

    const int t  = threadIdx.x;
    const int i  = blockIdx.x & 255;
    const int b0 = (blockIdx.x >> 8) * 256;

    const int l  = t & 63;
    const int wv = t >> 6;
    const int lg = l >> 4;
    const int lm = l & 15;

    aS[t] = A[t * NN + i];
    __syncthreads();

    // ---- fold W1s = diag(A[:,i])*W1 into frag-linear split-bf16 LDS [r8] ----
    #pragma unroll
    for (int fr = 0; fr < 8; ++fr) {
        const int f  = wv * 8 + fr;            // f = kb*4 + nt
        const int kb = f >> 2, nt = f & 3;
        const int h  = nt * 16 + lm;
        const int jb = kb * 32 + lg * 8;
        s16x8 hv, lv;
        #pragma unroll
        for (int w = 0; w < 8; ++w) {
            const int j = jb + w;
            const float pw = aS[j] * W1[j * HH + h];
            const unsigned short hb = f32_to_bf16_rne(pw);
            hv[w] = (short)hb;
            lv[w] = (short)f32_to_bf16_rne(pw - bf16_to_f32(hb));
        }
        *(s16x8*)(Bh + f * 512 + l * 8) = hv;
        *(s16x8*)(Bl + f * 512 + l * 8) = lv;
    }
    __syncthreads();

    // ---- MFMA1: 8 kb x 4 rt x 4 nt x 3 terms [r8] ----
    f32x4 acc[4][4];
    #pragma unroll
    for (int rt = 0; rt < 4; ++rt)
        #pragma unroll
        for (int nt = 0; nt < 4; ++nt) {
            acc[rt][nt][0] = 0.f; acc[rt][nt][1] = 0.f;
            acc[rt][nt][2] = 0.f; acc[rt][nt][3] = 0.f;
        }

    const int rowbase = b0 + wv * 64;
    for (int kb = 0; kb < 8; ++kb) {
        s16x8 bh[4], bl[4];
        #pragma unroll
        for (int nt = 0; nt < 4; ++nt) {
            const int sbase = ((kb * 4 + nt) * 64 + l) * 8;
            bh[nt] = *(const s16x8*)(Bh + sbase);
            bl[nt] = *(const s16x8*)(Bl + sbase);
        }
        const int koff = kb * 32 + lg * 8;
        #pragma unroll
        for (int rt = 0; rt < 4; ++rt) {
            const int row = rowbase + rt * 16 + lm;
            const s16x8 ah = *(const s16x8*)(xh + row * NN + koff);
            const s16x8 al = *(const s16x8*)(xl + row * NN + koff);
            #pragma unroll
            for (int nt = 0; nt < 4; ++nt) {
                acc[rt][nt] = __builtin_amdgcn_mfma_f32_16x16x32_bf16(ah, bh[nt], acc[rt][nt], 0, 0, 0);
                acc[rt][nt] = __builtin_amdgcn_mfma_f32_16x16x32_bf16(ah, bl[nt], acc[rt][nt], 0, 0, 0);
                acc[rt][nt] = __builtin_amdgcn_mfma_f32_16x16x32_bf16(al, bh[nt], acc[rt][nt], 0, 0, 0);
            }
        }
    }
    __syncthreads();   // B1 dead

    // ---- tr1: C-frags -> swizzled [256][64] [r8] ----
    #pragma unroll
    for (int rt = 0; rt < 4; ++rt)
        #pragma unroll
        for (int nt = 0; nt < 4; ++nt)
            #pragma unroll
            for (int rr = 0; rr < 4; ++rr) {
                const int wr  = wv * 64 + rt * 16 + lg * 4 + rr;
                const int col = nt * 16 + lm;
                const int q   = col >> 2;
                tr[wr * 64 + (((q ^ (wr & 15)) << 2) | (col & 3))] = acc[rt][nt][rr];
            }
    __syncthreads();

    // ---- readback rows ----
    float acc1[HH];
    #pragma unroll
    for (int q = 0; q < 16; ++q) {
        const f32x4 v = *(const f32x4*)&tr[t * 64 + ((q ^ (t & 15)) << 2)];
        acc1[4*q+0] = v[0]; acc1[4*q+1] = v[1]; acc1[4*q+2] = v[2]; acc1[4*q+3] = v[3];
    }
    __syncthreads();   // tr dead before A2 scatter

    // ---- + c, LN1, leaky [validated] ----
    {
        const float* crow = c + i * HH;
        #pragma unroll
        for (int h = 0; h < HH; ++h) acc1[h] += crow[h];
    }
    {
        float m0 = 0.f, m1 = 0.f, m2 = 0.f, m3 = 0.f;
        #pragma unroll
        for (int h = 0; h < HH; h += 4) { m0 += acc1[h]; m1 += acc1[h+1]; m2 += acc1[h+2]; m3 += acc1[h+3]; }
        const float m = (m0 + m1 + m2 + m3) * (1.f / HH);
        float v0 = 0.f, v1 = 0.f, v2 = 0.f, v3 = 0.f;
        #pragma unroll
        for (int h = 0; h < HH; h += 4) {
            float d0 = acc1[h] - m, d1 = acc1[h+1] - m, d2 = acc1[h+2] - m, d3 = acc1[h+3] - m;
            v0 = fmaf(d0, d0, v0); v1 = fmaf(d1, d1, v1); v2 = fmaf(d2, d2, v2); v3 = fmaf(d3, d3, v3);
        }
        const float var = (v0 + v1 + v2 + v3) * (1.f / HH);
        const float inv = rsqrtf(var + 1e-5f);
        #pragma unroll
        for (int h = 0; h < HH; ++h) {
            float u = (acc1[h] - m) * inv * g1[h] + bt1[h];
            acc1[h] = (u >= 0.f) ? u : 0.2f * u;
        }
    }

    // ---- split acc1 -> scatter A2 frags (r11 new) ----
    // thread t = row r: frag f2 = (r>>4)*2 + kk, lane slot = (w&3)*16 + (r&15)
    {
        const int f2base = (t >> 4) * 2;
        const int lm2    = t & 15;
        #pragma unroll
        for (int w = 0; w < 8; ++w) {
            const int kk = w >> 2, lg2 = w & 3;
            s16x8 hv, lv;
            #pragma unroll
            for (int e = 0; e < 8; ++e) {
                const float v = acc1[w * 8 + e];
                const unsigned short hb = f32_to_bf16_rne(v);
                hv[e] = (short)hb;
                lv[e] = (short)f32_to_bf16_rne(v - bf16_to_f32(hb));
            }
            const int base = (f2base + kk) * 512 + (lg2 * 16 + lm2) * 8;
            *(s16x8*)(Ah + base) = hv;
            *(s16x8*)(Al + base) = lv;
        }
    }
    __syncthreads();

    // ---- MFMA2: 2 kk x 4 rt x 4 nt x 3 terms (r11 new) ----
    f32x4 acc2[4][4];
    #pragma unroll
    for (int rt = 0; rt < 4; ++rt)
        #pragma unroll
        for (int nt = 0; nt < 4; ++nt) {
            acc2[rt][nt][0] = 0.f; acc2[rt][nt][1] = 0.f;
            acc2[rt][nt][2] = 0.f; acc2[rt][nt][3] = 0.f;
        }
    #pragma unroll
    for (int kk = 0; kk < 2; ++kk) {
        s16x8 b2h[4], b2l[4];
        #pragma unroll
        for (int nt = 0; nt < 4; ++nt) {
            const int off = (nt * 16 + lm) * HH + kk * 32 + lg * 8;
            b2h[nt] = *(const s16x8*)(w2h + off);
            b2l[nt] = *(const s16x8*)(w2l + off);
        }
        #pragma unroll
        for (int rt = 0; rt < 4; ++rt) {
            const int base = ((wv * 4 + rt) * 2 + kk) * 512 + l * 8;
            const s16x8 a2h = *(const s16x8*)(Ah + base);
            const s16x8 a2l = *(const s16x8*)(Al + base);
            #pragma unroll
            for (int nt = 0; nt < 4; ++nt) {
                acc2[rt][nt] = __builtin_amdgcn_mfma_f32_16x16x32_bf16(a2h, b2h[nt], acc2[rt][nt], 0, 0, 0);
                acc2[rt][nt] = __builtin_amdgcn_mfma_f32_16x16x32_bf16(a2h, b2l[nt], acc2[rt][nt], 0, 0, 0);
                acc2[rt][nt] = __builtin_amdgcn_mfma_f32_16x16x32_bf16(a2l, b2h[nt], acc2[rt][nt], 0, 0, 0);
            }
        }
    }
    __syncthreads();   // A2 dead

    // ---- tr2: acc2 frags -> swizzled rows ----
    #pragma unroll
    for (int rt = 0; rt < 4; ++rt)
        #pragma unroll
        for (int nt = 0; nt < 4; ++nt)
            #pragma unroll
            for (int rr = 0; rr < 4; ++rr) {
                const int wr  = wv * 64 + rt * 16 + lg * 4 + rr;
                const int col = nt * 16 + lm;
                const int q   = col >> 2;
                tr[wr * 64 + (((q ^ (wr & 15)) << 2) | (col & 3))] = acc2[rt][nt][rr];
            }
    __syncthreads();

    // ---- readback + b2, LN2, leaky, layer-3, store [validated] ----
    float accE[HH];
    #pragma unroll
    for (int q = 0; q < 16; ++q) {
        const f32x4 v = *(const f32x4*)&tr[t * 64 + ((q ^ (t & 15)) << 2)];
        accE[4*q+0] = v[0]; accE[4*q+1] = v[1]; accE[4*q+2] = v[2]; accE[4*q+3] = v[3];
    }
    #pragma unroll
    for (int h = 0; h < HH; ++h) accE[h] += b2[h];

    {
        float m0 = 0.f, m1 = 0.f, m2 = 0.f, m3 = 0.f;
        #pragma unroll
        for (int h = 0; h < HH; h += 4) { m0 += accE[h]; m1 += accE[h+1]; m2 += accE[h+2]; m3 += accE[h+3]; }
        const float m = (m0 + m1 + m2 + m3) * (1.f / HH);
        float v0 = 0.f, v1 = 0.f, v2 = 0.f, v3 = 0.f;
        #pragma unroll
        for (int h = 0; h < HH; h += 4) {
            float d0 = accE[h] - m, d1 = accE[h+1] - m, d2 = accE[h+2] - m, d3 = accE[h+3] - m;
            v0 = fmaf(d0, d0, v0); v1 = fmaf(d1, d1, v1); v2 = fmaf(d2, d2, v2); v3 = fmaf(d3, d3, v3);
        }
        const float var = (v0 + v1 + v2 + v3) * (1.f / HH);
        const float inv = rsqrtf(var + 1e-5f);
        #pragma unroll
        for (int h = 0; h < HH; ++h) {
            float u = (accE[h] - m) * inv * g2[h] + bt2[h];
            accE[h] = (u >= 0.f) ? u : 0.2f * u;
        }
    }

    float o0 = b3[0], o1 = b3[1];
    #pragma unroll
    for (int h = 0; h < HH; ++h) {
        o0 = fmaf(accE[h], W3[h * 2 + 0], o0);
        o1 = fmaf(accE[h], W3[h * 2 + 1], o1);
    }

    const int row = (b0 + t) * NN + i;
    out[row] = o0;
    out[BB * NN + row] = o1;
}

extern "C" void kernel_launch(void* const* d_in, const int* in_sizes, int n_in,
                              void* d_out, int out_size, void* d_ws, size_t ws_size,
                              hipStream_t stream) {
    const float* x   = (const float*)d_in[0];
    const float* A   = (const float*)d_in[1];
    const float* emb = (const float*)d_in[2];
    const float* W1  = (const float*)d_in[3];
    const float* b1  = (const float*)d_in[4];
    const float* g1  = (const float*)d_in[5];
    const float* bt1 = (const float*)d_in[6];
    const float* W2  = (const float*)d_in[7];
    const float* b2  = (const float*)d_in[8];
    const float* g2  = (const float*)d_in[9];
    const float* bt2 = (const float*)d_in[10];
    const float* W3  = (const float*)d_in[11];
    const float* b3  = (const float*)d_in[12];
    float* out = (float*)d_out;

    // ws carve: c (64 KB) | xh (1 MB) | xl (1 MB) | w2h (8 KB) | w2l (8 KB)
    float* c = (float*)d_ws;
    unsigned short* xhp = (unsigned short*)(c + NN * HH);
    unsigned short* xlp = xhp + BB * NN;
    unsigned short* w2hp = xlp + BB * NN;
    unsigned short* w2lp = w2hp + HH * HH;

    prep_x<<<(BB * NN) / 1024, 256, 0, stream>>>(x, xhp, xlp);
    prep_w2t<<<16, 256, 0, stream>>>(W2, w2hp, w2lp);
    precompute_c<<<NN, 256, 0, stream>>>(A, emb, W1, b1, c);
    fused_main<<<NN * (BB / 256), 256, 0, stream>>>(
        xhp, xlp, A, W1, c, w2hp, w2lp, g1, bt1, b2, g2, bt2, W3, b3, out);
}

// Round 13
// 191.053 us; speedup vs baseline: 1.9842x; 1.0302x over previous
//
#include <hip/hip_runtime.h>
#include <hip/hip_bf16.h>

#define BB 2048
#define NN 256
#define EE 32
#define HH 64

typedef __attribute__((ext_vector_type(8))) short s16x8;   // 8 bf16 = MFMA A/B frag
typedef __attribute__((ext_vector_type(4))) short s16x4;
typedef __attribute__((ext_vector_type(4))) float f32x4;   // MFMA C/D frag

// r13: compiler-friendly RNE convert — lets SLP pair adjacent converts into
// v_cvt_pk_bf16_f32 (hand-rolled bit-twiddle blocked this; ~10 VALU/elem).
__device__ __forceinline__ unsigned short f32_to_bf16_rne(float f) {
    __hip_bfloat16 h = __float2bfloat16(f);
    return *reinterpret_cast<unsigned short*>(&h);
}
__device__ __forceinline__ float bf16_to_f32(unsigned short h) {
    return __uint_as_float(((unsigned int)h) << 16);
}

// ---------------------------------------------------------------------------
// r13: ALL prep work in ONE launch (was 3 serialized launches ~70us w/ fused
// gap). Whole-block role split on blockIdx: no divergence.
//   bid [0,512)   : prep_x   — split x into hi/lo bf16          [validated r8]
//   bid [512,528) : prep_w2t — split W2^T into hi/lo bf16       [validated r12]
//   bid [528,784) : precompute_c — c[i][:] embedding fold       [validated r8]
// ---------------------------------------------------------------------------
__global__ __launch_bounds__(256) void prep_all(
    const float* __restrict__ x, const float* __restrict__ A,
    const float* __restrict__ emb, const float* __restrict__ W1,
    const float* __restrict__ b1, const float* __restrict__ W2,
    unsigned short* __restrict__ xh, unsigned short* __restrict__ xl,
    unsigned short* __restrict__ w2h, unsigned short* __restrict__ w2l,
    float* __restrict__ c) {

    __shared__ float aS[NN];
    __shared__ float red[256];
    __shared__ float peS[EE];

    const int bid = blockIdx.x;
    const int t   = threadIdx.x;

    if (bid < 512) {
        // ---- prep_x ----
        const int i4 = (bid * 256 + t) * 4;
        const f32x4 v = *(const f32x4*)(x + i4);
        s16x4 hv, lv;
        #pragma unroll
        for (int q = 0; q < 4; ++q) {
            const unsigned short hb = f32_to_bf16_rne(v[q]);
            hv[q] = (short)hb;
            lv[q] = (short)f32_to_bf16_rne(v[q] - bf16_to_f32(hb));
        }
        *(s16x4*)(xh + i4) = hv;
        *(s16x4*)(xl + i4) = lv;
    } else if (bid < 528) {
        // ---- prep_w2t ----
        const int idx = (bid - 512) * 256 + t;   // 0..4095
        const int n = idx >> 6, k = idx & 63;
        const float w = W2[k * HH + n];
        const unsigned short hb = f32_to_bf16_rne(w);
        w2h[n * HH + k] = hb;
        w2l[n * HH + k] = f32_to_bf16_rne(w - bf16_to_f32(hb));
    } else {
        // ---- precompute_c for i = bid-528 ----
        const int i = bid - 528;
        const float a_t = A[t * NN + i];
        aS[t] = a_t;
        red[t] = a_t;
        __syncthreads();
        #pragma unroll
        for (int s = 128; s > 0; s >>= 1) {
            if (t < s) red[t] += red[t + s];
            __syncthreads();
        }
        const float inv = 1.f / (red[0] + 1e-8f);

        const int e = t & 31, jg = t >> 5;
        float part = 0.f;
        #pragma unroll 8
        for (int r = 0; r < 32; ++r) {
            const int j = jg * 32 + r;
            part = fmaf(aS[j], emb[j * EE + e], part);
        }
        __syncthreads();
        red[t] = part;
        __syncthreads();
        if (t < 32) {
            float pe = 0.f;
            #pragma unroll
            for (int g = 0; g < 8; ++g) pe += red[g * 32 + t];
            peS[t] = pe * inv;
        }
        __syncthreads();

        if (t < HH) {
            float ch = b1[t];
            const float* embi = emb + i * EE;
            #pragma unroll 8
            for (int e2 = 0; e2 < EE; ++e2) {
                ch = fmaf(embi[e2], W1[(NN      + e2) * HH + t], ch);
                ch = fmaf(peS[e2],  W1[(NN + EE + e2) * HH + t], ch);
            }
            c[i * HH + t] = ch;
        }
    }
}

// ---------------------------------------------------------------------------
// Fused main [r12-validated structure, 126.5us]: both layers on MFMA with
// 3-term hi/lo split; one 64KB LDS union; 2 waves/SIMD operating point
// (register file: ~120 VGPR + 64 AGPR ~= 184/512 per-SIMD pool -> 2).
// r13 change: conversions via __float2bfloat16 (see helper above).
// Sequence: fold B1 -> MFMA1 -> tr1 -> rows -> LN1 -> scatter A2 -> MFMA2
//           -> tr2 -> rows -> LN2 -> W3 -> store.
// ---------------------------------------------------------------------------
__global__ __launch_bounds__(256, 2) void fused_main(
    const unsigned short* __restrict__ xh, const unsigned short* __restrict__ xl,
    const float* __restrict__ A, const float* __restrict__ W1,
    const float* __restrict__ c,
    const unsigned short* __restrict__ w2h, const unsigned short* __restrict__ w2l,
    const float* __restrict__ g1, const float* __restrict__ bt1,
    const float* __restrict__ b2,
    const float* __restrict__ g2, const float* __restrict__ bt2,
    const float* __restrict__ W3, const float* __restrict__ b3,
    float* __restrict__ out) {

    __shared__ float smem[16384];      // 64 KB union: B1 / tr / A2
    __shared__ float aS[NN];           // A[:,i]
    unsigned short* Bh = (unsigned short*)smem;   // 32 frags * 512 shorts
    unsigned short* Bl = Bh + 32 * 512;
    float* tr = smem;                             // [256][64] swizzled
    unsigned short* Ah = (unsigned short*)smem;   // layer-2 A frags
    unsigned short* Al = Ah + 32 * 512;

    const int t  = threadIdx.x;
    const int i  = blockIdx.x & 255;
    const int b0 = (blockIdx.x >> 8) * 256;

    const int l  = t & 63;
    const int wv = t >> 6;
    const int lg = l >> 4;
    const int lm = l & 15;

    aS[t] = A[t * NN + i];
    __syncthreads();

    // ---- fold W1s = diag(A[:,i])*W1 into frag-linear split-bf16 LDS ----
    #pragma unroll
    for (int fr = 0; fr < 8; ++fr) {
        const int f  = wv * 8 + fr;            // f = kb*4 + nt
        const int kb = f >> 2, nt = f & 3;
        const int h  = nt * 16 + lm;
        const int jb = kb * 32 + lg * 8;
        s16x8 hv, lv;
        #pragma unroll
        for (int w = 0; w < 8; ++w) {
            const int j = jb + w;
            const float pw = aS[j] * W1[j * HH + h];
            const unsigned short hb = f32_to_bf16_rne(pw);
            hv[w] = (short)hb;
            lv[w] = (short)f32_to_bf16_rne(pw - bf16_to_f32(hb));
        }
        *(s16x8*)(Bh + f * 512 + l * 8) = hv;
        *(s16x8*)(Bl + f * 512 + l * 8) = lv;
    }
    __syncthreads();

    // ---- MFMA1: 8 kb x 4 rt x 4 nt x 3 terms ----
    f32x4 acc[4][4];
    #pragma unroll
    for (int rt = 0; rt < 4; ++rt)
        #pragma unroll
        for (int nt = 0; nt < 4; ++nt) {
            acc[rt][nt][0] = 0.f; acc[rt][nt][1] = 0.f;
            acc[rt][nt][2] = 0.f; acc[rt][nt][3] = 0.f;
        }

    const int rowbase = b0 + wv * 64;
    for (int kb = 0; kb < 8; ++kb) {
        s16x8 bh[4], bl[4];
        #pragma unroll
        for (int nt = 0; nt < 4; ++nt) {
            const int sbase = ((kb * 4 + nt) * 64 + l) * 8;
            bh[nt] = *(const s16x8*)(Bh + sbase);
            bl[nt] = *(const s16x8*)(Bl + sbase);
        }
        const int koff = kb * 32 + lg * 8;
        #pragma unroll
        for (int rt = 0; rt < 4; ++rt) {
            const int row = rowbase + rt * 16 + lm;
            const s16x8 ah = *(const s16x8*)(xh + row * NN + koff);
            const s16x8 al = *(const s16x8*)(xl + row * NN + koff);
            #pragma unroll
            for (int nt = 0; nt < 4; ++nt) {
                acc[rt][nt] = __builtin_amdgcn_mfma_f32_16x16x32_bf16(ah, bh[nt], acc[rt][nt], 0, 0, 0);
                acc[rt][nt] = __builtin_amdgcn_mfma_f32_16x16x32_bf16(ah, bl[nt], acc[rt][nt], 0, 0, 0);
                acc[rt][nt] = __builtin_amdgcn_mfma_f32_16x16x32_bf16(al, bh[nt], acc[rt][nt], 0, 0, 0);
            }
        }
    }
    __syncthreads();   // B1 dead

    // ---- tr1: C-frags -> swizzled [256][64] ----
    #pragma unroll
    for (int rt = 0; rt < 4; ++rt)
        #pragma unroll
        for (int nt = 0; nt < 4; ++nt)
            #pragma unroll
            for (int rr = 0; rr < 4; ++rr) {
                const int wr  = wv * 64 + rt * 16 + lg * 4 + rr;
                const int col = nt * 16 + lm;
                const int q   = col >> 2;
                tr[wr * 64 + (((q ^ (wr & 15)) << 2) | (col & 3))] = acc[rt][nt][rr];
            }
    __syncthreads();

    // ---- readback rows ----
    float acc1[HH];
    #pragma unroll
    for (int q = 0; q < 16; ++q) {
        const f32x4 v = *(const f32x4*)&tr[t * 64 + ((q ^ (t & 15)) << 2)];
        acc1[4*q+0] = v[0]; acc1[4*q+1] = v[1]; acc1[4*q+2] = v[2]; acc1[4*q+3] = v[3];
    }
    __syncthreads();   // tr dead before A2 scatter

    // ---- + c, LN1, leaky ----
    {
        const float* crow = c + i * HH;
        #pragma unroll
        for (int h = 0; h < HH; ++h) acc1[h] += crow[h];
    }
    {
        float m0 = 0.f, m1 = 0.f, m2 = 0.f, m3 = 0.f;
        #pragma unroll
        for (int h = 0; h < HH; h += 4) { m0 += acc1[h]; m1 += acc1[h+1]; m2 += acc1[h+2]; m3 += acc1[h+3]; }
        const float m = (m0 + m1 + m2 + m3) * (1.f / HH);
        float v0 = 0.f, v1 = 0.f, v2 = 0.f, v3 = 0.f;
        #pragma unroll
        for (int h = 0; h < HH; h += 4) {
            float d0 = acc1[h] - m, d1 = acc1[h+1] - m, d2 = acc1[h+2] - m, d3 = acc1[h+3] - m;
            v0 = fmaf(d0, d0, v0); v1 = fmaf(d1, d1, v1); v2 = fmaf(d2, d2, v2); v3 = fmaf(d3, d3, v3);
        }
        const float var = (v0 + v1 + v2 + v3) * (1.f / HH);
        const float inv = rsqrtf(var + 1e-5f);
        #pragma unroll
        for (int h = 0; h < HH; ++h) {
            float u = (acc1[h] - m) * inv * g1[h] + bt1[h];
            acc1[h] = (u >= 0.f) ? u : 0.2f * u;
        }
    }

    // ---- split acc1 -> scatter A2 frags ----
    {
        const int f2base = (t >> 4) * 2;
        const int lm2    = t & 15;
        #pragma unroll
        for (int w = 0; w < 8; ++w) {
            const int kk = w >> 2, lg2 = w & 3;
            s16x8 hv, lv;
            #pragma unroll
            for (int e = 0; e < 8; ++e) {
                const float v = acc1[w * 8 + e];
                const unsigned short hb = f32_to_bf16_rne(v);
                hv[e] = (short)hb;
                lv[e] = (short)f32_to_bf16_rne(v - bf16_to_f32(hb));
            }
            const int base = (f2base + kk) * 512 + (lg2 * 16 + lm2) * 8;
            *(s16x8*)(Ah + base) = hv;
            *(s16x8*)(Al + base) = lv;
        }
    }
    __syncthreads();

    // ---- MFMA2: 2 kk x 4 rt x 4 nt x 3 terms ----
    f32x4 acc2[4][4];
    #pragma unroll
    for (int rt = 0; rt < 4; ++rt)
        #pragma unroll
        for (int nt = 0; nt < 4; ++nt) {
            acc2[rt][nt][0] = 0.f; acc2[rt][nt][1] = 0.f;
            acc2[rt][nt][2] = 0.f; acc2[rt][nt][3] = 0.f;
        }
    #pragma unroll
    for (int kk = 0; kk < 2; ++kk) {
        s16x8 b2h[4], b2l[4];
        #pragma unroll
        for (int nt = 0; nt < 4; ++nt) {
            const int off = (nt * 16 + lm) * HH + kk * 32 + lg * 8;
            b2h[nt] = *(const s16x8*)(w2h + off);
            b2l[nt] = *(const s16x8*)(w2l + off);
        }
        #pragma unroll
        for (int rt = 0; rt < 4; ++rt) {
            const int base = ((wv * 4 + rt) * 2 + kk) * 512 + l * 8;
            const s16x8 a2h = *(const s16x8*)(Ah + base);
            const s16x8 a2l = *(const s16x8*)(Al + base);
            #pragma unroll
            for (int nt = 0; nt < 4; ++nt) {
                acc2[rt][nt] = __builtin_amdgcn_mfma_f32_16x16x32_bf16(a2h, b2h[nt], acc2[rt][nt], 0, 0, 0);
                acc2[rt][nt] = __builtin_amdgcn_mfma_f32_16x16x32_bf16(a2h, b2l[nt], acc2[rt][nt], 0, 0, 0);
                acc2[rt][nt] = __builtin_amdgcn_mfma_f32_16x16x32_bf16(a2l, b2h[nt], acc2[rt][nt], 0, 0, 0);
            }
        }
    }
    __syncthreads();   // A2 dead

    // ---- tr2: acc2 frags -> swizzled rows ----
    #pragma unroll
    for (int rt = 0; rt < 4; ++rt)
        #pragma unroll
        for (int nt = 0; nt < 4; ++nt)
            #pragma unroll
            for (int rr = 0; rr < 4; ++rr) {
                const int wr  = wv * 64 + rt * 16 + lg * 4 + rr;
                const int col = nt * 16 + lm;
                const int q   = col >> 2;
                tr[wr * 64 + (((q ^ (wr & 15)) << 2) | (col & 3))] = acc2[rt][nt][rr];
            }
    __syncthreads();

    // ---- readback + b2, LN2, leaky, layer-3, store ----
    float accE[HH];
    #pragma unroll
    for (int q = 0; q < 16; ++q) {
        const f32x4 v = *(const f32x4*)&tr[t * 64 + ((q ^ (t & 15)) << 2)];
        accE[4*q+0] = v[0]; accE[4*q+1] = v[1]; accE[4*q+2] = v[2]; accE[4*q+3] = v[3];
    }
    #pragma unroll
    for (int h = 0; h < HH; ++h) accE[h] += b2[h];

    {
        float m0 = 0.f, m1 = 0.f, m2 = 0.f, m3 = 0.f;
        #pragma unroll
        for (int h = 0; h < HH; h += 4) { m0 += accE[h]; m1 += accE[h+1]; m2 += accE[h+2]; m3 += accE[h+3]; }
        const float m = (m0 + m1 + m2 + m3) * (1.f / HH);
        float v0 = 0.f, v1 = 0.f, v2 = 0.f, v3 = 0.f;
        #pragma unroll
        for (int h = 0; h < HH; h += 4) {
            float d0 = accE[h] - m, d1 = accE[h+1] - m, d2 = accE[h+2] - m, d3 = accE[h+3] - m;
            v0 = fmaf(d0, d0, v0); v1 = fmaf(d1, d1, v1); v2 = fmaf(d2, d2, v2); v3 = fmaf(d3, d3, v3);
        }
        const float var = (v0 + v1 + v2 + v3) * (1.f / HH);
        const float inv = rsqrtf(var + 1e-5f);
        #pragma unroll
        for (int h = 0; h < HH; ++h) {
            float u = (accE[h] - m) * inv * g2[h] + bt2[h];
            accE[h] = (u >= 0.f) ? u : 0.2f * u;
        }
    }

    float o0 = b3[0], o1 = b3[1];
    #pragma unroll
    for (int h = 0; h < HH; ++h) {
        o0 = fmaf(accE[h], W3[h * 2 + 0], o0);
        o1 = fmaf(accE[h], W3[h * 2 + 1], o1);
    }

    const int row = (b0 + t) * NN + i;
    out[row] = o0;
    out[BB * NN + row] = o1;
}

extern "C" void kernel_launch(void* const* d_in, const int* in_sizes, int n_in,
                              void* d_out, int out_size, void* d_ws, size_t ws_size,
                              hipStream_t stream) {
    const float* x   = (const float*)d_in[0];
    const float* A   = (const float*)d_in[1];
    const float* emb = (const float*)d_in[2];
    const float* W1  = (const float*)d_in[3];
    const float* b1  = (const float*)d_in[4];
    const float* g1  = (const float*)d_in[5];
    const float* bt1 = (const float*)d_in[6];
    const float* W2  = (const float*)d_in[7];
    const float* b2  = (const float*)d_in[8];
    const float* g2  = (const float*)d_in[9];
    const float* bt2 = (const float*)d_in[10];
    const float* W3  = (const float*)d_in[11];
    const float* b3  = (const float*)d_in[12];
    float* out = (float*)d_out;

    // ws carve: c (64 KB) | xh (1 MB) | xl (1 MB) | w2h (8 KB) | w2l (8 KB)
    float* c = (float*)d_ws;
    unsigned short* xhp = (unsigned short*)(c + NN * HH);
    unsigned short* xlp = xhp + BB * NN;
    unsigned short* w2hp = xlp + BB * NN;
    unsigned short* w2lp = w2hp + HH * HH;

    prep_all<<<784, 256, 0, stream>>>(x, A, emb, W1, b1, W2,
                                      xhp, xlp, w2hp, w2lp, c);
    fused_main<<<NN * (BB / 256), 256, 0, stream>>>(
        xhp, xlp, A, W1, c, w2hp, w2lp, g1, bt1, b2, g2, bt2, W3, b3, out);
}